// Round 6
// baseline (295.282 us; speedup 1.0000x reference)
//
#include <hip/hip_runtime.h>

#define N_NODES 50000
#define E_EDGES 800000
#define SCAN_NBLK 196   // ceil(50000/256)

// ---------------- CSR build ----------------

__global__ void k_count(const int* __restrict__ dst, int* __restrict__ cnt) {
    int e = blockIdx.x * blockDim.x + threadIdx.x;
    if (e < E_EDGES) atomicAdd(&cnt[dst[e]], 1);
}

// phase A: per-block exclusive scan of cnt -> excl (in-place ok), block sums -> bsum
__global__ void k_scan_part(const int* __restrict__ cnt, int* __restrict__ excl,
                            int* __restrict__ bsum) {
    __shared__ int sm[256];
    int b = blockIdx.x, t = threadIdx.x;
    int i = b * 256 + t;
    int v = (i < N_NODES) ? cnt[i] : 0;
    sm[t] = v;
    __syncthreads();
    for (int off = 1; off < 256; off <<= 1) {
        int u = (t >= off) ? sm[t - off] : 0;
        __syncthreads();
        sm[t] += u;
        __syncthreads();
    }
    if (i < N_NODES) excl[i] = sm[t] - v;
    if (t == 255) bsum[b] = sm[255];
}

// phase B: exclusive scan of the block sums (SCAN_NBLK <= 256)
__global__ void k_scan_bsum(const int* __restrict__ bsum, int* __restrict__ boff) {
    __shared__ int sm[256];
    int t = threadIdx.x;
    int v = (t < SCAN_NBLK) ? bsum[t] : 0;
    sm[t] = v;
    __syncthreads();
    for (int off = 1; off < 256; off <<= 1) {
        int u = (t >= off) ? sm[t - off] : 0;
        __syncthreads();
        sm[t] += u;
        __syncthreads();
    }
    if (t < SCAN_NBLK) boff[t] = sm[t] - v;
}

// phase C: add block offsets, produce rowptr + cursor
__global__ void k_scan_add(int* __restrict__ rowptr, const int* __restrict__ boff,
                           int* __restrict__ cursor) {
    int b = blockIdx.x, t = threadIdx.x;
    int i = b * 256 + t;
    if (i < N_NODES) {
        int r = rowptr[i] + boff[b];
        rowptr[i] = r;
        cursor[i] = r;
    }
    if (i == 0) rowptr[N_NODES] = E_EDGES;
}

__global__ void k_fill(const int* __restrict__ src, const int* __restrict__ dst,
                       int* __restrict__ cursor, int* __restrict__ eidx) {
    int e = blockIdx.x * blockDim.x + threadIdx.x;
    if (e < E_EDGES) {
        int p = atomicAdd(&cursor[dst[e]], 1);
        eidx[p] = src[e];
    }
}

// ---------------- weights ----------------

// WT[k*ldd + col_off + o] = W[o*K + k]
__global__ void k_transpose(const float* __restrict__ W, float* __restrict__ WT,
                            int O, int K, int ldd, int col_off) {
    int idx = blockIdx.x * blockDim.x + threadIdx.x;
    if (idx < O * K) {
        int o = idx / K, k = idx - o * K;
        WT[k * ldd + col_off + o] = W[idx];
    }
}

// ---------------- gathers ----------------

// mean[i,o] = (1/max(deg,1)) * sum_{j in N(i)} x[j,o]   (128 threads / node)
__global__ void k_gather128(const int* __restrict__ rowptr, const int* __restrict__ eidx,
                            const float* __restrict__ x, float* __restrict__ mean) {
    int i = blockIdx.x;
    int o = threadIdx.x;
    int beg = rowptr[i], end = rowptr[i + 1];
    float acc = 0.0f;
    int j = beg;
    for (; j + 3 < end; j += 4) {
        int s0 = eidx[j], s1 = eidx[j + 1], s2 = eidx[j + 2], s3 = eidx[j + 3];
        float v0 = x[(size_t)s0 * 128 + o];
        float v1 = x[(size_t)s1 * 128 + o];
        float v2 = x[(size_t)s2 * 128 + o];
        float v3 = x[(size_t)s3 * 128 + o];
        acc += v0 + v1 + v2 + v3;
    }
    for (; j < end; ++j)
        acc += x[(size_t)eidx[j] * 128 + o];
    float inv = 1.0f / fmaxf((float)(end - beg), 1.0f);
    mean[(size_t)i * 128 + o] = acc * inv;
}

// out[i,o] = z[i,80][40+o] + inv * sum_{j in N(i)} z[j,80][o]   (o < 40)
// block = 320 threads = 8 nodes x 40 lanes (zero idle lanes; grid*8 == N exactly)
__global__ void k_gather40(const int* __restrict__ rowptr, const int* __restrict__ eidx,
                           const float* __restrict__ z, float* __restrict__ out) {
    int t = threadIdx.x;
    int i = blockIdx.x * 8 + t / 40;
    int o = t % 40;
    int beg = rowptr[i], end = rowptr[i + 1];
    float acc = 0.0f;
    int j = beg;
    for (; j + 3 < end; j += 4) {
        int s0 = eidx[j], s1 = eidx[j + 1], s2 = eidx[j + 2], s3 = eidx[j + 3];
        float v0 = z[(size_t)s0 * 80 + o];
        float v1 = z[(size_t)s1 * 80 + o];
        float v2 = z[(size_t)s2 * 80 + o];
        float v3 = z[(size_t)s3 * 80 + o];
        acc += v0 + v1 + v2 + v3;
    }
    for (; j < end; ++j)
        acc += z[(size_t)eidx[j] * 80 + o];
    float inv = 1.0f / fmaxf((float)(end - beg), 1.0f);
    out[(size_t)i * 40 + o] = z[(size_t)i * 80 + 40 + o] + acc * inv;
}

// ---------------- layer 1 dense ----------------
// h[M,128] = relu( [mean | x][M,256] @ B1cat[256,128] + b1 )
// BM=32 (grid 1563 -> ~6 blocks/CU), 256 thr: og=t&15 -> cols {og*4..+3, 64+og*4..+3}
// (2-way bank alias only = free), mg=t>>4 -> 2 nodes each. BK=64, 4 K-tiles.
__launch_bounds__(256)
__global__ void k_dense1(const float* __restrict__ mean, const float* __restrict__ x,
                         const float* __restrict__ Bcat,  // [256][128]
                         const float* __restrict__ b1, float* __restrict__ h) {
    __shared__ float Bs[64][128];
    int t = threadIdx.x;
    int og = t & 15, mg = t >> 4;
    int og4 = og * 4;
    int node0 = blockIdx.x * 32 + mg * 2;

    int mr0 = min(node0 + 0, N_NODES - 1);
    int mr1 = min(node0 + 1, N_NODES - 1);

    float acc[2][8];
#pragma unroll
    for (int j = 0; j < 2; ++j)
#pragma unroll
        for (int q = 0; q < 8; ++q) acc[j][q] = 0.0f;

    for (int kt = 0; kt < 4; ++kt) {
        const float* __restrict__ Asrc = (kt < 2) ? mean : x;
        int kbase = (kt & 1) * 64;

        __syncthreads();
        {
            const float4* src = (const float4*)(Bcat + kt * 64 * 128);
            float4* dst = (float4*)&Bs[0][0];
#pragma unroll
            for (int p = 0; p < 8; ++p)
                dst[t + p * 256] = src[t + p * 256];
        }
        __syncthreads();

        const float* a0 = Asrc + (size_t)mr0 * 128 + kbase;
        const float* a1 = Asrc + (size_t)mr1 * 128 + kbase;

#pragma unroll 4
        for (int k4 = 0; k4 < 16; ++k4) {
            float4 av0 = *(const float4*)(a0 + k4 * 4);
            float4 av1 = *(const float4*)(a1 + k4 * 4);

#pragma unroll
            for (int u = 0; u < 4; ++u) {
                int kk = k4 * 4 + u;
                float4 bq0 = *(const float4*)&Bs[kk][og4];
                float4 bq1 = *(const float4*)&Bs[kk][64 + og4];
                float e0 = (u == 0) ? av0.x : (u == 1) ? av0.y : (u == 2) ? av0.z : av0.w;
                float e1 = (u == 0) ? av1.x : (u == 1) ? av1.y : (u == 2) ? av1.z : av1.w;
                acc[0][0] = fmaf(e0, bq0.x, acc[0][0]);
                acc[0][1] = fmaf(e0, bq0.y, acc[0][1]);
                acc[0][2] = fmaf(e0, bq0.z, acc[0][2]);
                acc[0][3] = fmaf(e0, bq0.w, acc[0][3]);
                acc[0][4] = fmaf(e0, bq1.x, acc[0][4]);
                acc[0][5] = fmaf(e0, bq1.y, acc[0][5]);
                acc[0][6] = fmaf(e0, bq1.z, acc[0][6]);
                acc[0][7] = fmaf(e0, bq1.w, acc[0][7]);
                acc[1][0] = fmaf(e1, bq0.x, acc[1][0]);
                acc[1][1] = fmaf(e1, bq0.y, acc[1][1]);
                acc[1][2] = fmaf(e1, bq0.z, acc[1][2]);
                acc[1][3] = fmaf(e1, bq0.w, acc[1][3]);
                acc[1][4] = fmaf(e1, bq1.x, acc[1][4]);
                acc[1][5] = fmaf(e1, bq1.y, acc[1][5]);
                acc[1][6] = fmaf(e1, bq1.z, acc[1][6]);
                acc[1][7] = fmaf(e1, bq1.w, acc[1][7]);
            }
        }
    }

    float bias[8];
#pragma unroll
    for (int q = 0; q < 4; ++q) bias[q] = b1[og4 + q];
#pragma unroll
    for (int q = 0; q < 4; ++q) bias[4 + q] = b1[64 + og4 + q];

#pragma unroll
    for (int j = 0; j < 2; ++j) {
        int m = node0 + j;
        if (m < N_NODES) {
            float4 r0, r1;
            r0.x = fmaxf(acc[j][0] + bias[0], 0.0f);
            r0.y = fmaxf(acc[j][1] + bias[1], 0.0f);
            r0.z = fmaxf(acc[j][2] + bias[2], 0.0f);
            r0.w = fmaxf(acc[j][3] + bias[3], 0.0f);
            r1.x = fmaxf(acc[j][4] + bias[4], 0.0f);
            r1.y = fmaxf(acc[j][5] + bias[5], 0.0f);
            r1.z = fmaxf(acc[j][6] + bias[6], 0.0f);
            r1.w = fmaxf(acc[j][7] + bias[7], 0.0f);
            *(float4*)&h[(size_t)m * 128 + og4] = r0;
            *(float4*)&h[(size_t)m * 128 + 64 + og4] = r1;
        }
    }
}

// ---------------- layer 2 dense ----------------
// z[M,80] = h[M,128] @ B2cat[128,80];  cols >=40 get +b2
// BM=32 (grid 1563), 256 thr: og=t&7 (10 cols), mg=t>>3 (1 node). K=128 one tile.
__launch_bounds__(256)
__global__ void k_dense2(const float* __restrict__ h,
                         const float* __restrict__ Bcat,  // [128][80]
                         const float* __restrict__ b2, float* __restrict__ z) {
    __shared__ float Bs[128][80];
    int t = threadIdx.x;
    int og = t & 7, mg = t >> 3;
    int o0 = og * 10;
    int node = blockIdx.x * 32 + mg;
    int mc = min(node, N_NODES - 1);

    {
        const float4* src = (const float4*)Bcat;
        float4* dst = (float4*)&Bs[0][0];
#pragma unroll
        for (int p = 0; p < 10; ++p)
            dst[t + p * 256] = src[t + p * 256];
    }
    __syncthreads();

    float acc[10];
#pragma unroll
    for (int q = 0; q < 10; ++q) acc[q] = 0.0f;

    const float* a = h + (size_t)mc * 128;

#pragma unroll 4
    for (int kk = 0; kk < 128; ++kk) {
        float av = a[kk];
        float bv[10];
#pragma unroll
        for (int q = 0; q < 5; ++q) {
            float2 b2v = *(const float2*)&Bs[kk][o0 + 2 * q];
            bv[2 * q] = b2v.x;
            bv[2 * q + 1] = b2v.y;
        }
#pragma unroll
        for (int q = 0; q < 10; ++q)
            acc[q] = fmaf(av, bv[q], acc[q]);
    }

    if (node < N_NODES) {
#pragma unroll
        for (int q = 0; q < 5; ++q) {
            int o = o0 + 2 * q;
            float2 r;
            r.x = acc[2 * q]     + ((o     >= 40) ? b2[o - 40]     : 0.0f);
            r.y = acc[2 * q + 1] + ((o + 1 >= 40) ? b2[o + 1 - 40] : 0.0f);
            *(float2*)&z[(size_t)node * 80 + o] = r;
        }
    }
}

// ---------------- launch ----------------

extern "C" void kernel_launch(void* const* d_in, const int* in_sizes, int n_in,
                              void* d_out, int out_size, void* d_ws, size_t ws_size,
                              hipStream_t stream) {
    const float* x   = (const float*)d_in[0];
    const int*   ei  = (const int*)d_in[1];      // [2, E] int32
    const float* W1l = (const float*)d_in[2];
    const float* b1  = (const float*)d_in[3];
    const float* W1r = (const float*)d_in[4];
    const float* W2l = (const float*)d_in[5];
    const float* b2  = (const float*)d_in[6];
    const float* W2r = (const float*)d_in[7];

    const int* src = ei;
    const int* dst = ei + E_EDGES;

    // ---- workspace carve (16B-aligned) ----
    char* base = (char*)d_ws;
    size_t off = 0;
    auto carve = [&](size_t bytes) {
        void* p = base + off;
        off += (bytes + 15) & ~(size_t)15;
        return p;
    };
    int*   cnt    = (int*)  carve((size_t)N_NODES * 4);
    int*   rowptr = (int*)  carve((size_t)(N_NODES + 1) * 4);
    int*   cursor = (int*)  carve((size_t)N_NODES * 4);
    int*   eidx   = (int*)  carve((size_t)E_EDGES * 4);
    int*   bsum   = (int*)  carve((size_t)256 * 4);
    int*   boff   = (int*)  carve((size_t)256 * 4);
    float* b1cat  = (float*)carve((size_t)256 * 128 * 4);   // [256][128]
    float* b2cat  = (float*)carve((size_t)128 * 80 * 4);    // [128][80]
    float* mean   = (float*)carve((size_t)N_NODES * 128 * 4);
    float* h      = (float*)carve((size_t)N_NODES * 128 * 4);
    float* z      = mean;   // mean dead after k_dense1; z is N*80 < N*128
    float* outp   = (float*)d_out;

    // ---- CSR build ----
    hipMemsetAsync(cnt, 0, (size_t)N_NODES * 4, stream);
    k_count<<<(E_EDGES + 255) / 256, 256, 0, stream>>>(dst, cnt);
    k_scan_part<<<SCAN_NBLK, 256, 0, stream>>>(cnt, rowptr, bsum);
    k_scan_bsum<<<1, 256, 0, stream>>>(bsum, boff);
    k_scan_add<<<SCAN_NBLK, 256, 0, stream>>>(rowptr, boff, cursor);
    k_fill<<<(E_EDGES + 255) / 256, 256, 0, stream>>>(src, dst, cursor, eidx);

    // ---- weight prep ----
    k_transpose<<<(16384 + 255) / 256, 256, 0, stream>>>(W1l, b1cat, 128, 128, 128, 0);
    k_transpose<<<(16384 + 255) / 256, 256, 0, stream>>>(W1r, b1cat + 128 * 128, 128, 128, 128, 0);
    k_transpose<<<(5120 + 255) / 256, 256, 0, stream>>>(W2l, b2cat, 40, 128, 80, 0);
    k_transpose<<<(5120 + 255) / 256, 256, 0, stream>>>(W2r, b2cat, 40, 128, 80, 40);

    // ---- layer 1 ----
    k_gather128<<<N_NODES, 128, 0, stream>>>(rowptr, eidx, x, mean);
    k_dense1<<<(N_NODES + 31) / 32, 256, 0, stream>>>(mean, x, b1cat, b1, h);

    // ---- layer 2 ----
    k_dense2<<<(N_NODES + 31) / 32, 256, 0, stream>>>(h, b2cat, b2, z);
    k_gather40<<<(N_NODES + 7) / 8, 320, 0, stream>>>(rowptr, eidx, z, outp);
}